// Round 3
// baseline (336.509 us; speedup 1.0000x reference)
//
#include <hip/hip_runtime.h>
#include <cstddef>
#include <cstdint>

// Channel-interleaved SAT: sat[(y*1025 + x)*8 + c], y,x in [0,1025), c in [0,8).
#define SATW 1025
#define W8   8200          // 1025 * 8 floats per y-row
#define NCH  8
#define ROWS 16            // y-rows per chain chunk
#define NCHUNK 64          // 1024 / ROWS
#define NSLICE 9           // ceil(8200 / 1024) column slices
#define SLICEW 1024        // columns per slice (4 per thread)

#define SAT_BYTES ((size_t)SATW * W8 * 4)
#define CTRL_OFF  ((SAT_BYTES + 255) & ~(size_t)255)
#define CTRL_INTS (16 + NSLICE * NCHUNK)          // tickets[16] + flags[9*64]
#define AGG_OFF   (CTRL_OFF + 4096)
#define AGG_BYTES ((size_t)NSLICE * NCHUNK * SLICEW * 8)
#define INCL_OFF  (AGG_OFF + AGG_BYTES)

// ---------------- Kernel A: row prefix sums, planar in -> interleaved out ----
// One block per y. Block 0 also zeroes the chain-control words (tickets+flags)
// for the colscan kernel (kernel-boundary ordering makes this safe).
__global__ __launch_bounds__(256) void rowscan_kernel(const float* __restrict__ in,
                                                      float* __restrict__ sat,
                                                      int* __restrict__ ctrl) {
    const int y    = blockIdx.x;
    const int t    = threadIdx.x;
    const int lane = t & 63;
    const int wv   = t >> 6;

    if (y == 0) {
        for (int i = t; i < CTRL_INTS; i += 256) ctrl[i] = 0;
    }

    __shared__ float lds[NCH][1024];

    for (int k = 0; k < 2; ++k) {
        const int c = wv * 2 + k;
        const float4* r4 = (const float4*)(in + ((size_t)c * 1024 + y) * 1024);
        double chunkbase = 0.0;
#pragma unroll
        for (int j = 0; j < 4; ++j) {           // 4 chunks of 256 floats
            float4 a = r4[lane + 64 * j];
            double v0 = a.x, v1 = a.y, v2 = a.z, v3 = a.w;
            double s = v0 + v1 + v2 + v3;
            double ps = s;
#pragma unroll
            for (int off = 1; off < 64; off <<= 1) {
                double n = __shfl_up(ps, off, 64);
                if (lane >= off) ps += n;
            }
            double base = chunkbase + ps - s;
            double p0 = base + v0, p1 = p0 + v1, p2 = p1 + v2, p3 = p2 + v3;
            ((float4*)lds[c])[lane + 64 * j] =
                make_float4((float)p0, (float)p1, (float)p2, (float)p3);
            chunkbase += __shfl(ps, 63, 64);
        }
    }
    __syncthreads();

    // Interleaved row write: flat f -> x = f>>3, c = f&7; val = x ? prefix[x-1] : 0
    float* orow = sat + (size_t)(y + 1) * W8;
    for (int f4 = t; f4 < W8 / 4; f4 += 256) {
        int f = f4 * 4;
        float4 o;
        float* po = (float*)&o;
#pragma unroll
        for (int j = 0; j < 4; ++j) {
            int ff = f + j;
            int x = ff >> 3, c = ff & 7;
            po[j] = x ? lds[c][x - 1] : 0.0f;
        }
        ((float4*)orow)[f4] = o;
    }
}

// ---------------- Kernel B: chained column scan (decoupled lookback) ---------
// Grid (NSLICE, NCHUNK). Ticket-ordered chunk assignment per slice; each block
// reads its 16 rows once into registers, publishes f64 column aggregates,
// accumulates predecessor aggregates until an inclusive flag, writes final SAT.
__global__ __launch_bounds__(256) void colscan_chained(float* __restrict__ sat,
                                                       double* __restrict__ agg,
                                                       double* __restrict__ incl,
                                                       int* __restrict__ ctrl) {
    const int slice = blockIdx.x;
    const int t     = threadIdx.x;
    int* tickets = ctrl;
    int* flags   = ctrl + 16;

    __shared__ int sh_chunk;
    if (t == 0) sh_chunk = atomicAdd(&tickets[slice], 1);
    __syncthreads();
    const int chunk = sh_chunk;

    const int  col = slice * SLICEW + t * 4;
    const bool act = col < W8;

    float4 r[ROWS];
    double s0 = 0, s1 = 0, s2 = 0, s3 = 0;
    float* base = sat + (size_t)(1 + chunk * ROWS) * W8 + col;
    if (act) {
#pragma unroll
        for (int i = 0; i < ROWS; ++i) {
            r[i] = *(const float4*)(base + (size_t)i * W8);
            s0 += r[i].x; s1 += r[i].y; s2 += r[i].z; s3 += r[i].w;
        }
    }

    const size_t vo  = ((size_t)slice * NCHUNK + chunk) * SLICEW + (size_t)t * 4;
    int*         flg = &flags[slice * NCHUNK + chunk];
    double e0 = 0, e1 = 0, e2 = 0, e3 = 0;   // exclusive column prefix

    if (chunk == 0) {
        __hip_atomic_store(&incl[vo + 0], s0, __ATOMIC_RELAXED, __HIP_MEMORY_SCOPE_AGENT);
        __hip_atomic_store(&incl[vo + 1], s1, __ATOMIC_RELAXED, __HIP_MEMORY_SCOPE_AGENT);
        __hip_atomic_store(&incl[vo + 2], s2, __ATOMIC_RELAXED, __HIP_MEMORY_SCOPE_AGENT);
        __hip_atomic_store(&incl[vo + 3], s3, __ATOMIC_RELAXED, __HIP_MEMORY_SCOPE_AGENT);
        __threadfence();
        __syncthreads();
        if (t == 0) __hip_atomic_store(flg, 2, __ATOMIC_RELEASE, __HIP_MEMORY_SCOPE_AGENT);
    } else {
        __hip_atomic_store(&agg[vo + 0], s0, __ATOMIC_RELAXED, __HIP_MEMORY_SCOPE_AGENT);
        __hip_atomic_store(&agg[vo + 1], s1, __ATOMIC_RELAXED, __HIP_MEMORY_SCOPE_AGENT);
        __hip_atomic_store(&agg[vo + 2], s2, __ATOMIC_RELAXED, __HIP_MEMORY_SCOPE_AGENT);
        __hip_atomic_store(&agg[vo + 3], s3, __ATOMIC_RELAXED, __HIP_MEMORY_SCOPE_AGENT);
        __threadfence();
        __syncthreads();
        if (t == 0) __hip_atomic_store(flg, 1, __ATOMIC_RELEASE, __HIP_MEMORY_SCOPE_AGENT);

        __shared__ int sh_st;
        for (int p = chunk - 1; ; --p) {
            if (t == 0) {
                int st;
                do {
                    st = __hip_atomic_load(&flags[slice * NCHUNK + p],
                                           __ATOMIC_ACQUIRE, __HIP_MEMORY_SCOPE_AGENT);
                } while (st == 0);
                sh_st = st;
            }
            __syncthreads();
            const int st = sh_st;
            __syncthreads();                 // protect sh_st before next overwrite
            const double* src = (st == 2 ? incl : agg) +
                                ((size_t)slice * NCHUNK + p) * SLICEW + (size_t)t * 4;
            e0 += __hip_atomic_load(&src[0], __ATOMIC_RELAXED, __HIP_MEMORY_SCOPE_AGENT);
            e1 += __hip_atomic_load(&src[1], __ATOMIC_RELAXED, __HIP_MEMORY_SCOPE_AGENT);
            e2 += __hip_atomic_load(&src[2], __ATOMIC_RELAXED, __HIP_MEMORY_SCOPE_AGENT);
            e3 += __hip_atomic_load(&src[3], __ATOMIC_RELAXED, __HIP_MEMORY_SCOPE_AGENT);
            if (st == 2) break;
        }
        __hip_atomic_store(&incl[vo + 0], e0 + s0, __ATOMIC_RELAXED, __HIP_MEMORY_SCOPE_AGENT);
        __hip_atomic_store(&incl[vo + 1], e1 + s1, __ATOMIC_RELAXED, __HIP_MEMORY_SCOPE_AGENT);
        __hip_atomic_store(&incl[vo + 2], e2 + s2, __ATOMIC_RELAXED, __HIP_MEMORY_SCOPE_AGENT);
        __hip_atomic_store(&incl[vo + 3], e3 + s3, __ATOMIC_RELAXED, __HIP_MEMORY_SCOPE_AGENT);
        __threadfence();
        __syncthreads();
        if (t == 0) __hip_atomic_store(flg, 2, __ATOMIC_RELEASE, __HIP_MEMORY_SCOPE_AGENT);
    }

    if (act) {
        if (chunk == 0) *(float4*)(sat + col) = make_float4(0.f, 0.f, 0.f, 0.f);
        double r0 = e0, r1 = e1, r2 = e2, r3 = e3;
#pragma unroll
        for (int i = 0; i < ROWS; ++i) {
            r0 += r[i].x; r1 += r[i].y; r2 += r[i].z; r3 += r[i].w;
            *(float4*)(base + (size_t)i * W8) =
                make_float4((float)r0, (float)r1, (float)r2, (float)r3);
        }
    }
}

// ---------------- Kernel C: one wave per ROI, all 8 channels -----------------
__global__ __launch_bounds__(256) void pool_kernel(const float* __restrict__ sat,
                                                   const int* __restrict__ rois,
                                                   float* __restrict__ out,
                                                   int n_roi) {
    int lane = threadIdx.x & 63;
    int roi  = (blockIdx.x * blockDim.x + threadIdx.x) >> 6;
    if (roi >= n_roi) return;

    const int4 rv = ((const int4*)rois)[roi];   // [y0, x0, y1, x1] pixel coords
    int ymin = rv.x >> 5;                       // / FEAT_STRIDE(32)
    int xmin = rv.y >> 5;
    int Ly   = (rv.z >> 5) + 1 - ymin;
    int Lx   = (rv.w >> 5) + 1 - xmin;

    double acc[NCH];
#pragma unroll
    for (int c = 0; c < NCH; ++c) acc[c] = 0.0;

    if (lane < 49) {
        int by = lane / 7;
        int bx = lane - by * 7;
        int ylo = ymin + (by * Ly) / 7;
        int yhi = ymin + ((by + 1) * Ly + 6) / 7;
        int xlo = xmin + (bx * Lx) / 7;
        int xhi = xmin + ((bx + 1) * Lx + 6) / 7;
        double inv = 1.0 / (double)((yhi - ylo) * (xhi - xlo));

        float4 a[2], b[2], c4[2], d[2];
        const float4* hh = (const float4*)(sat + ((size_t)yhi * SATW + xhi) * NCH);
        const float4* lh = (const float4*)(sat + ((size_t)ylo * SATW + xhi) * NCH);
        const float4* hl = (const float4*)(sat + ((size_t)yhi * SATW + xlo) * NCH);
        const float4* ll = (const float4*)(sat + ((size_t)ylo * SATW + xlo) * NCH);
        a[0] = hh[0]; a[1] = hh[1];
        b[0] = lh[0]; b[1] = lh[1];
        c4[0] = hl[0]; c4[1] = hl[1];
        d[0] = ll[0]; d[1] = ll[1];
        const float* fa = (const float*)a;
        const float* fb = (const float*)b;
        const float* fc = (const float*)c4;
        const float* fd = (const float*)d;
#pragma unroll
        for (int c = 0; c < NCH; ++c) {
            double v = (double)fa[c] - (double)fb[c] - (double)fc[c] + (double)fd[c];
            acc[c] = v * inv;
        }
    }

#pragma unroll
    for (int off = 32; off; off >>= 1) {
#pragma unroll
        for (int c = 0; c < NCH; ++c) acc[c] += __shfl_down(acc[c], off, 64);
    }

    if (lane == 0) {
        float4* po = (float4*)(out + (size_t)roi * NCH);
        po[0] = make_float4((float)(acc[0] * (1.0 / 49.0)),
                            (float)(acc[1] * (1.0 / 49.0)),
                            (float)(acc[2] * (1.0 / 49.0)),
                            (float)(acc[3] * (1.0 / 49.0)));
        po[1] = make_float4((float)(acc[4] * (1.0 / 49.0)),
                            (float)(acc[5] * (1.0 / 49.0)),
                            (float)(acc[6] * (1.0 / 49.0)),
                            (float)(acc[7] * (1.0 / 49.0)));
    }
}

extern "C" void kernel_launch(void* const* d_in, const int* in_sizes, int n_in,
                              void* d_out, int out_size, void* d_ws, size_t ws_size,
                              hipStream_t stream) {
    const float* conv = (const float*)d_in[0];   // (1, 8, 1024, 1024) f32
    const int*   rois = (const int*)d_in[1];     // (8192, 4) int32
    float*       out  = (float*)d_out;           // (8192, 2, 4) f32 flat
    int n_roi = in_sizes[1] / 4;

    float*  sat  = (float*)d_ws;
    int*    ctrl = (int*)((char*)d_ws + CTRL_OFF);
    double* agg  = (double*)((char*)d_ws + AGG_OFF);
    double* incl = (double*)((char*)d_ws + INCL_OFF);

    rowscan_kernel<<<1024, 256, 0, stream>>>(conv, sat, ctrl);
    colscan_chained<<<dim3(NSLICE, NCHUNK), 256, 0, stream>>>(sat, agg, incl, ctrl);
    pool_kernel<<<(n_roi + 3) / 4, 256, 0, stream>>>(sat, rois, out, n_roi);
}

// Round 5
// 124.508 us; speedup vs baseline: 2.7027x; 2.7027x over previous
//
#include <hip/hip_runtime.h>
#include <cstddef>
#include <cstdint>

// Channel-interleaved SAT: sat[(y*1025 + x)*8 + c], y,x in [0,1025), c in [0,8).
// sat[y][x][c] = sum over rows<y, cols<x of channel c.
#define SATW 1025
#define W8   8200          // 1025 * 8 floats per y-row
#define NCH  8
#define NCHUNK 64          // chunks over y (== wave size, for the wave scan)
#define RR   16            // 1024 / NCHUNK rows per chunk

#define SAT_BYTES ((size_t)SATW * W8 * 4)
#define PART_OFF  ((SAT_BYTES + 255) & ~(size_t)255)

// ---------------- Kernel A: row prefix sums, planar in -> interleaved out ----
// One block per y. 4 waves; wave w scans channels 2w and 2w+1 independently
// (chunked wave scan, f64 accumulate), stages to LDS, then a fully-coalesced
// float4 write of the 32.8 KB interleaved row.
__global__ __launch_bounds__(256) void rowscan_kernel(const float* __restrict__ in,
                                                      float* __restrict__ sat) {
    const int y    = blockIdx.x;
    const int t    = threadIdx.x;
    const int lane = t & 63;
    const int wv   = t >> 6;

    __shared__ float lds[NCH][1024];

    for (int k = 0; k < 2; ++k) {
        const int c = wv * 2 + k;
        const float4* r4 = (const float4*)(in + ((size_t)c * 1024 + y) * 1024);
        double chunkbase = 0.0;
#pragma unroll
        for (int j = 0; j < 4; ++j) {           // 4 chunks of 256 floats
            float4 a = r4[lane + 64 * j];       // coalesced per instruction
            double v0 = a.x, v1 = a.y, v2 = a.z, v3 = a.w;
            double s = v0 + v1 + v2 + v3;
            double ps = s;                      // inclusive scan of lane sums
#pragma unroll
            for (int off = 1; off < 64; off <<= 1) {
                double n = __shfl_up(ps, off, 64);
                if (lane >= off) ps += n;
            }
            double base = chunkbase + ps - s;   // exclusive prefix for this lane
            double p0 = base + v0, p1 = p0 + v1, p2 = p1 + v2, p3 = p2 + v3;
            ((float4*)lds[c])[lane + 64 * j] =
                make_float4((float)p0, (float)p1, (float)p2, (float)p3);
            chunkbase += __shfl(ps, 63, 64);    // chunk total broadcast
        }
    }
    __syncthreads();

    // Interleaved row write: flat f -> x = f>>3, c = f&7; val = x ? prefix[x-1] : 0
    float* orow = sat + (size_t)(y + 1) * W8;
    for (int f4 = t; f4 < W8 / 4; f4 += 256) {
        int f = f4 * 4;
        float4 o;
        float* po = (float*)&o;
#pragma unroll
        for (int j = 0; j < 4; ++j) {
            int ff = f + j;
            int x = ff >> 3, c = ff & 7;
            po[j] = x ? lds[c][x - 1] : 0.0f;   // 2-way LDS alias: free
        }
        ((float4*)orow)[f4] = o;                // coalesced global store
    }
}

// ---------------- Kernel B1: per-column chunk sums (RR rows per chunk) -------
// grid = dim3(33, NCHUNK). Column = flat (x,c) index f; row stride = W8.
__global__ void colsum_kernel(const float* __restrict__ sat,
                              double* __restrict__ partial) {
    int f  = blockIdx.x * 256 + threadIdx.x;
    int ch = blockIdx.y;
    if (f >= W8) return;
    const float* p = sat + ((size_t)(1 + ch * RR)) * W8 + f;
    double s = 0.0;
#pragma unroll 4
    for (int i = 0; i < RR; ++i) s += (double)p[(size_t)i * W8];
    partial[(size_t)ch * W8 + f] = s;
}

// ---------------- Kernel B2: wave-per-column exclusive scan over chunks ------
// One wave per column; lane ch owns chunk ch. 1 load + 6 shuffles + 1 store.
__global__ __launch_bounds__(256) void scanpartial_wave(double* __restrict__ partial) {
    int col  = (blockIdx.x * blockDim.x + threadIdx.x) >> 6;
    int lane = threadIdx.x & 63;
    if (col >= W8) return;
    double v = partial[(size_t)lane * W8 + col];
    double ps = v;
#pragma unroll
    for (int off = 1; off < 64; off <<= 1) {
        double n = __shfl_up(ps, off, 64);
        if (lane >= off) ps += n;
    }
    partial[(size_t)lane * W8 + col] = ps - v;   // exclusive prefix
}

// ---------------- Kernel B3: propagate — inclusive column scan per chunk -----
__global__ void colscan_kernel(float* __restrict__ sat,
                               const double* __restrict__ partial) {
    int f  = blockIdx.x * 256 + threadIdx.x;
    int ch = blockIdx.y;
    if (f >= W8) return;
    double run = partial[(size_t)ch * W8 + f];
    if (ch == 0) sat[f] = 0.0f;             // SAT row y=0 is zeros
    float* p = sat + ((size_t)(1 + ch * RR)) * W8 + f;
#pragma unroll 4
    for (int i = 0; i < RR; ++i) {
        run += (double)p[(size_t)i * W8];
        p[(size_t)i * W8] = (float)run;
    }
}

// ---------------- Kernel C: one wave per ROI, all 8 channels -----------------
// Lane<49 owns one 7x7 bin: 4 corners x 8 interleaved channels (2 float4 each).
__global__ __launch_bounds__(256) void pool_kernel(const float* __restrict__ sat,
                                                   const int* __restrict__ rois,
                                                   float* __restrict__ out,
                                                   int n_roi) {
    int lane = threadIdx.x & 63;
    int roi  = (blockIdx.x * blockDim.x + threadIdx.x) >> 6;
    if (roi >= n_roi) return;

    const int4 rv = ((const int4*)rois)[roi];   // [y0, x0, y1, x1] pixel coords
    int ymin = rv.x >> 5;                       // / FEAT_STRIDE(32)
    int xmin = rv.y >> 5;
    int Ly   = (rv.z >> 5) + 1 - ymin;
    int Lx   = (rv.w >> 5) + 1 - xmin;

    double acc[NCH];
#pragma unroll
    for (int c = 0; c < NCH; ++c) acc[c] = 0.0;

    if (lane < 49) {
        int by = lane / 7;
        int bx = lane - by * 7;
        int ylo = ymin + (by * Ly) / 7;
        int yhi = ymin + ((by + 1) * Ly + 6) / 7;
        int xlo = xmin + (bx * Lx) / 7;
        int xhi = xmin + ((bx + 1) * Lx + 6) / 7;
        double inv = 1.0 / (double)((yhi - ylo) * (xhi - xlo));

        float4 a[2], b[2], c4[2], d[2];
        const float4* hh = (const float4*)(sat + ((size_t)yhi * SATW + xhi) * NCH);
        const float4* lh = (const float4*)(sat + ((size_t)ylo * SATW + xhi) * NCH);
        const float4* hl = (const float4*)(sat + ((size_t)yhi * SATW + xlo) * NCH);
        const float4* ll = (const float4*)(sat + ((size_t)ylo * SATW + xlo) * NCH);
        a[0] = hh[0]; a[1] = hh[1];
        b[0] = lh[0]; b[1] = lh[1];
        c4[0] = hl[0]; c4[1] = hl[1];
        d[0] = ll[0]; d[1] = ll[1];
        const float* fa = (const float*)a;
        const float* fb = (const float*)b;
        const float* fc = (const float*)c4;
        const float* fd = (const float*)d;
#pragma unroll
        for (int c = 0; c < NCH; ++c) {
            double v = (double)fa[c] - (double)fb[c] - (double)fc[c] + (double)fd[c];
            acc[c] = v * inv;
        }
    }

#pragma unroll
    for (int off = 32; off; off >>= 1) {
#pragma unroll
        for (int c = 0; c < NCH; ++c) acc[c] += __shfl_down(acc[c], off, 64);
    }

    if (lane == 0) {
        float4* po = (float4*)(out + (size_t)roi * NCH);
        po[0] = make_float4((float)(acc[0] * (1.0 / 49.0)),
                            (float)(acc[1] * (1.0 / 49.0)),
                            (float)(acc[2] * (1.0 / 49.0)),
                            (float)(acc[3] * (1.0 / 49.0)));
        po[1] = make_float4((float)(acc[4] * (1.0 / 49.0)),
                            (float)(acc[5] * (1.0 / 49.0)),
                            (float)(acc[6] * (1.0 / 49.0)),
                            (float)(acc[7] * (1.0 / 49.0)));
    }
}

extern "C" void kernel_launch(void* const* d_in, const int* in_sizes, int n_in,
                              void* d_out, int out_size, void* d_ws, size_t ws_size,
                              hipStream_t stream) {
    const float* conv = (const float*)d_in[0];   // (1, 8, 1024, 1024) f32
    const int*   rois = (const int*)d_in[1];     // (8192, 4) int32
    float*       out  = (float*)d_out;           // (8192, 2, 4) f32 flat
    int n_roi = in_sizes[1] / 4;

    float*  sat     = (float*)d_ws;
    double* partial = (double*)((char*)d_ws + PART_OFF);   // 64 * 8200 f64 = 4.2 MB

    rowscan_kernel<<<1024, 256, 0, stream>>>(conv, sat);
    colsum_kernel<<<dim3(33, NCHUNK), 256, 0, stream>>>(sat, partial);
    scanpartial_wave<<<(W8 * 64 + 255) / 256, 256, 0, stream>>>(partial);
    colscan_kernel<<<dim3(33, NCHUNK), 256, 0, stream>>>(sat, partial);
    pool_kernel<<<(n_roi + 3) / 4, 256, 0, stream>>>(sat, rois, out, n_roi);
}